// Round 2
// baseline (182.871 us; speedup 1.0000x reference)
//
#include <hip/hip_runtime.h>
#include <math.h>

#define TSEQ 2048
#define HIDDEN 1280
#define NH 16
#define HD 80
#define HDP 96
#define ATTN_SCALE 0.11180339887498949f

typedef __bf16 bf16x8 __attribute__((ext_vector_type(8)));
typedef float f32x4 __attribute__((ext_vector_type(4)));

__device__ inline float bf2f(ushort u){ union { unsigned int u; float f; } v; v.u = ((unsigned int)u) << 16; return v.f; }
__device__ inline ushort f2bf(float f){
  union { float f; unsigned int u; } v; v.f = f;
  unsigned int u = v.u;
  return (ushort)((u + 0x7fffu + ((u >> 16) & 1u)) >> 16);
}
__device__ inline float ldin(const void* p, size_t i, bool f32){
  return f32 ? ((const float*)p)[i] : bf2f(((const ushort*)p)[i]);
}
// async global->LDS, 16B per lane; lds base must be wave-uniform, lane i lands at base + i*16B
__device__ inline void gl_lds16(const ushort* gp, ushort* lds_base){
  __builtin_amdgcn_global_load_lds(
      (const __attribute__((address_space(1))) unsigned int*)gp,
      (__attribute__((address_space(3))) unsigned int*)lds_base, 16, 0, 0);
}

// ---------------- misc: dtype detect (block 0) + segment bounds (blocks 1..8) ----------------
__global__ void misc_k(const ushort* __restrict__ X, const int* __restrict__ seg,
                       int* __restrict__ flag, int* __restrict__ segS, int* __restrict__ segE){
  int b = blockIdx.x, tid = threadIdx.x;
  if (b == 0){
    int insane = 0;
    for (int i = tid; i < 2048; i += 256){
      ushort u = X[i];
      int e = (u >> 7) & 0xFF;
      int m = u & 0x7F;
      bool bad = (e >= 0xC0) || (e != 0 && e <= 0x30) || (e == 0 && m != 0);
      if (bad) insane++;
    }
    __shared__ int s[256];
    s[tid] = insane; __syncthreads();
    for (int st = 128; st > 0; st >>= 1){ if (tid < st) s[tid] += s[tid + st]; __syncthreads(); }
    if (tid == 0) *flag = (s[0] > 128) ? 1 : 0;   // 1 => fp32 inputs
  } else {
    int t = (b - 1) * 256 + tid;
    int id = seg[t];
    int lo = 0, hi = TSEQ;
    while (lo < hi){ int mid = (lo + hi) >> 1; if (seg[mid] < id) lo = mid + 1; else hi = mid; }
    segS[t] = lo;
    lo = 0; hi = TSEQ;
    while (lo < hi){ int mid = (lo + hi) >> 1; if (seg[mid] <= id) lo = mid + 1; else hi = mid; }
    segE[t] = lo;
  }
}

// ---------------- prep: X convert (blocks 0..2559) + WT1 (2560..7359) + WT2 (7360..8959) ----
__global__ void prep_k(const int* __restrict__ flag, const void* __restrict__ X,
                       const void* __restrict__ Wq, const void* __restrict__ Wp,
                       ushort* __restrict__ Xb, ushort* __restrict__ WT1, ushort* __restrict__ WT2){
  __shared__ ushort tile[32][33];
  const bool f32 = (*flag != 0);
  int b = blockIdx.x, tid = threadIdx.x;
  if (b < 2560){
    int i = (b * 256 + tid) * 4;
    ushort o[4];
    if (f32){
      float4 v = *reinterpret_cast<const float4*>((const float*)X + i);
      o[0] = f2bf(v.x); o[1] = f2bf(v.y); o[2] = f2bf(v.z); o[3] = f2bf(v.w);
    } else {
      *reinterpret_cast<ushort4*>(o) = *reinterpret_cast<const ushort4*>((const ushort*)X + i);
    }
    *reinterpret_cast<ushort4*>(Xb + i) = *reinterpret_cast<ushort4*>(o);
    return;
  }
  const void* in; ushort* out; int rows, cols, tb;
  if (b < 7360){ tb = b - 2560; in = Wq; out = WT1; rows = HIDDEN; cols = 3 * HIDDEN; }
  else         { tb = b - 7360; in = Wp; out = WT2; rows = HIDDEN; cols = HIDDEN; }
  int tpr = cols / 32;
  int bx = (tb % tpr) * 32, by = (tb / tpr) * 32;
  int tx = tid & 31, ty = tid >> 5;
  for (int i = ty; i < 32; i += 8){
    size_t idx = (size_t)(by + i) * cols + bx + tx;
    tile[i][tx] = f32 ? f2bf(((const float*)in)[idx]) : ((const ushort*)in)[idx];
  }
  __syncthreads();
  for (int i = ty; i < 32; i += 8)
    out[(size_t)(bx + i) * rows + by + tx] = tile[tx][i];
}

// ---------------- GEMM: C[M,N] = A[M,K] @ BT[N,K]^T + bias ----------------
// BK=64, dbuf LDS, global_load_lds staging gated by raw vmcnt(N) barriers (AITER-style),
// 8-group XOR bank swizzle. MODE 0: bf16 out. MODE 1: out dtype per flag.
// BN: 128 (4 waves, 64x64 each) or 64 (4 waves, 64x32 each).
template<int MODE, int BN>
__launch_bounds__(256, 2)
__global__ void gemm_k(const ushort* __restrict__ A, const ushort* __restrict__ BT,
                       const void* __restrict__ bias, int K, int N,
                       const int* __restrict__ flagp, void* __restrict__ out)
{
  constexpr int NFJ = (BN == 128) ? 4 : 2;   // n-fragments per wave
  constexpr int BDM = (BN == 128) ? 4 : 2;   // B DMAs per wave per tile (8 rows each)
  __shared__ __align__(16) ushort As[2][128 * 64];
  __shared__ __align__(16) ushort Bs[2][BN * 64];
  const int tid = threadIdx.x;
  const int wave = tid >> 6, lane = tid & 63;
  const int quad = lane >> 4, c = lane & 15;
  const int m0 = blockIdx.y * 128, n0 = blockIdx.x * BN;
  const int wm = (wave & 1) * 64, wn = (wave >> 1) * (BN / 2);

  f32x4 acc[4][NFJ];
  for (int i = 0; i < 4; i++) for (int j = 0; j < NFJ; j++) acc[i][j] = (f32x4){0.f,0.f,0.f,0.f};

  const int drow = lane >> 3;
  const int dcg  = lane & 7;
  const int L8   = ((dcg ^ drow) * 8);
  const int brow = wave * (BN / 4);          // B staging row base for this wave
  const ushort* Ab = A  + (size_t)(m0 + wave * 32 + drow) * K + L8;
  const ushort* Bb = BT + (size_t)(n0 + brow + drow) * K + L8;
  const size_t row8 = (size_t)8 * K;
  const int woffA = wave * 32 * 64;
  const int woffB = brow * 64;

  // prologue: stage tile 0 into buffer 0 (4+BDM DMAs per wave)
  for (int d = 0; d < 4; d++)   gl_lds16(Ab + d * row8, As[0] + woffA + d * 512);
  for (int d = 0; d < BDM; d++) gl_lds16(Bb + d * row8, Bs[0] + woffB + d * 512);

  int cur = 0;
  for (int k0 = 0; k0 < K; k0 += 64){
    if (k0 + 64 < K){
      int nxt = cur ^ 1;
      for (int d = 0; d < 4; d++)   gl_lds16(Ab + d * row8 + k0 + 64, As[nxt] + woffA + d * 512);
      for (int d = 0; d < BDM; d++) gl_lds16(Bb + d * row8 + k0 + 64, Bs[nxt] + woffB + d * 512);
      // wait only for the PREVIOUS tile's DMAs; the fresh ones stay in flight
      if constexpr (BN == 128)
        asm volatile("s_waitcnt vmcnt(8)\ns_barrier" ::: "memory");
      else
        asm volatile("s_waitcnt vmcnt(6)\ns_barrier" ::: "memory");
    } else {
      asm volatile("s_waitcnt vmcnt(0)\ns_barrier" ::: "memory");
    }
    const ushort* Ac = As[cur];
    const ushort* Bc = Bs[cur];
    for (int ks = 0; ks < 2; ks++){
      const int pq8 = (((ks * 4 + quad) ^ (c & 7)) * 8);
      bf16x8 af[4], bfv[NFJ];
      for (int i = 0; i < 4; i++)   af[i]  = *reinterpret_cast<const bf16x8*>(&Ac[(wm + i*16 + c) * 64 + pq8]);
      for (int j = 0; j < NFJ; j++) bfv[j] = *reinterpret_cast<const bf16x8*>(&Bc[(wn + j*16 + c) * 64 + pq8]);
      for (int i = 0; i < 4; i++)
        for (int j = 0; j < NFJ; j++)
          acc[i][j] = __builtin_amdgcn_mfma_f32_16x16x32_bf16(af[i], bfv[j], acc[i][j], 0, 0, 0);
    }
    // all waves must finish reading 'cur' before next iteration's DMA overwrites it
    asm volatile("s_waitcnt lgkmcnt(0)\ns_barrier" ::: "memory");
    cur ^= 1;
  }

  const bool f32 = (*flagp != 0);

  for (int j = 0; j < NFJ; j++){
    int n = n0 + wn + j*16 + c;
    float bv = ldin(bias, n, f32);
    for (int i = 0; i < 4; i++){
      int mbase = m0 + wm + i*16 + quad*4;
      for (int rr = 0; rr < 4; rr++){
        float v = acc[i][j][rr] + bv;
        size_t idx = (size_t)(mbase + rr) * N + n;
        if (MODE == 1 && f32) ((float*)out)[idx] = v;
        else                  ((ushort*)out)[idx] = f2bf(v);
      }
    }
  }
}

// ---------------- reshape: RoPE Q/K (blocks 0..2047) + V transpose (2048..2559) ------------
__global__ void reshape_k(const int* __restrict__ flag, const ushort* __restrict__ qkv,
                          const void* __restrict__ rope,
                          ushort* __restrict__ Qh, ushort* __restrict__ Kh, ushort* __restrict__ Vt){
  __shared__ __align__(16) ushort shm[5632];
  int b = blockIdx.x, tid = threadIdx.x;
  if (b < 2048){
    ushort* row = shm;           // 3840
    ushort* rrow = shm + 3840;   // 40
    int t = b;
    for (int i = tid; i < 480; i += 256)
      *reinterpret_cast<uint4*>(&row[i * 8]) = *reinterpret_cast<const uint4*>(qkv + (size_t)t * 3840 + i * 8);
    if (tid < 40)
      rrow[tid] = f2bf(ldin(rope, t * 40 + tid, *flag != 0));
    __syncthreads();
    int w = tid;
    if (w < 160){
      int part = w / 80;                 // 0=Q, 1=K
      int hw = w - part * 80;
      int h = hw / 5, dr0 = (hw % 5) * 8;
      const ushort* src = &row[part * HIDDEN + h * HD];
      ushort* dst = (part ? Kh : Qh) + ((size_t)h * TSEQ + t) * HDP;
      ushort o0[8], o1[8];
      for (int d = 0; d < 8; d++){
        float th = bf2f(rrow[dr0 + d]);
        float cs, sn;
        __sincosf(th, &sn, &cs);         // v_sin_f32/v_cos_f32 — theta ~ N(0,1), fast path exact to bf16
        float xr = bf2f(src[dr0 + d]);
        float xi = bf2f(src[dr0 + d + 40]);
        o0[d] = f2bf(xr * cs - xi * sn);
        o1[d] = f2bf(xr * sn + xi * cs);
      }
      *reinterpret_cast<uint4*>(dst + dr0)      = *reinterpret_cast<uint4*>(o0);
      *reinterpret_cast<uint4*>(dst + dr0 + 40) = *reinterpret_cast<uint4*>(o1);
    } else if (w < 224){
      int idx = w - 160;                 // 64 items: {Q,K} x 16h x 2seg
      int part = idx >> 5;
      int h = (idx & 31) >> 1, sg = idx & 1;
      ushort* dst = (part ? Kh : Qh) + ((size_t)h * TSEQ + t) * HDP + 80 + sg * 8;
      uint4 z = {0, 0, 0, 0};
      *reinterpret_cast<uint4*>(dst) = z;
    }
  } else {
    int vb = b - 2048;
    int h = vb & 15, t0 = (vb >> 4) * 64;
    const ushort* src = qkv + 2 * HIDDEN + h * HD;
    // tile[64][88]
    for (int w = tid; w < 640; w += 256){
      int r = w / 10, cc = (w % 10) * 8;
      *reinterpret_cast<uint4*>(&shm[r * 88 + cc]) = *reinterpret_cast<const uint4*>(src + (size_t)(t0 + r) * 3840 + cc);
    }
    __syncthreads();
    for (int w = tid; w < 320; w += 256){
      int d = w >> 2, sg = (w & 3) * 16;
      ushort tmp[16];
      for (int i = 0; i < 16; i++) tmp[i] = shm[(sg + i) * 88 + d];
      ushort* dst = Vt + ((size_t)h * HD + d) * TSEQ + t0 + sg;
      *reinterpret_cast<uint4*>(dst)     = *reinterpret_cast<uint4*>(tmp);
      *reinterpret_cast<uint4*>(dst + 8) = *reinterpret_cast<uint4*>(tmp + 8);
    }
  }
}

// ---------------- attention: 16 q/tile, 2 waves split the k-range (additive partials) ------
__launch_bounds__(128, 4)
__global__ void attn_k(const ushort* __restrict__ Qh, const ushort* __restrict__ Kh,
                       const ushort* __restrict__ Vt, const int* __restrict__ seg,
                       const int* __restrict__ segS, const int* __restrict__ segE,
                       ushort* __restrict__ Oh)
{
  __shared__ __align__(16) ushort Pm[2][2][512];   // [wave][dbuf][16*32]
  __shared__ float accS[5][64][4];                 // wave1 partial O
  __shared__ float lsumS[64][4];                   // wave1 partial l
  int tid = threadIdx.x;
  int wave = tid >> 6, lane = tid & 63;
  int quad = lane >> 4, c = lane & 15;
  int b = blockIdx.x;
  int xcd = b & 7, slot = b >> 3;
  int h = slot & 15;
  int t0 = (xcd * 16 + (slot >> 4)) * 16;

  const ushort* Qb = Qh + (size_t)h * TSEQ * HDP;
  const ushort* Kb = Kh + (size_t)h * TSEQ * HDP;
  const ushort* Vb = Vt + (size_t)h * HD * TSEQ;

  bf16x8 aq[3];
  for (int i = 0; i < 3; i++)
    aq[i] = *reinterpret_cast<const bf16x8*>(Qb + (size_t)(t0 + c) * HDP + i * 32 + quad * 8);

  int segq[4];
  for (int rr = 0; rr < 4; rr++) segq[rr] = seg[t0 + quad * 4 + rr];

  int kstart = segS[t0] & ~31;
  int kend   = segE[t0 + 15];

  float lsum[4] = {0.f, 0.f, 0.f, 0.f};
  f32x4 accd[5];
  for (int dt = 0; dt < 5; dt++) accd[dt] = (f32x4){0.f,0.f,0.f,0.f};

  for (int kt = kstart + wave * 32; kt < kend; kt += 64){
    ushort* pm = &Pm[wave][(kt >> 6) & 1][0];
    // cluster all 6 K-fragment loads, then the QK^T MFMAs
    bf16x8 bk[6];
    for (int i = 0; i < 3; i++){
      bk[i]     = *reinterpret_cast<const bf16x8*>(Kb + (size_t)(kt + c) * HDP + i * 32 + quad * 8);
      bk[3 + i] = *reinterpret_cast<const bf16x8*>(Kb + (size_t)(kt + 16 + c) * HDP + i * 32 + quad * 8);
    }
    f32x4 s0 = (f32x4){0.f,0.f,0.f,0.f}, s1 = (f32x4){0.f,0.f,0.f,0.f};
    __builtin_amdgcn_s_setprio(1);
    for (int i = 0; i < 3; i++){
      s0 = __builtin_amdgcn_mfma_f32_16x16x32_bf16(aq[i], bk[i],     s0, 0, 0, 0);
      s1 = __builtin_amdgcn_mfma_f32_16x16x32_bf16(aq[i], bk[3 + i], s1, 0, 0, 0);
    }
    __builtin_amdgcn_s_setprio(0);
    // hoist V-fragment loads: independent of P, so their latency overlaps exp + LDS round-trip
    bf16x8 bv[5];
    for (int dt = 0; dt < 5; dt++)
      bv[dt] = *reinterpret_cast<const bf16x8*>(Vb + (size_t)(dt * 16 + c) * TSEQ + kt + quad * 8);
    int segk0 = seg[kt + c];
    int segk1 = seg[kt + 16 + c];
    for (int rr = 0; rr < 4; rr++){
      bool ok0 = (segq[rr] == segk0);
      bool ok1 = (segq[rr] == segk1);
      float e0 = ok0 ? __expf(fminf(s0[rr] * ATTN_SCALE, 30.f)) : 0.f;
      float e1 = ok1 ? __expf(fminf(s1[rr] * ATTN_SCALE, 30.f)) : 0.f;
      ushort u0 = f2bf(e0), u1 = f2bf(e1);
      lsum[rr] += bf2f(u0) + bf2f(u1);
      pm[(quad * 4 + rr) * 32 + c]      = u0;
      pm[(quad * 4 + rr) * 32 + 16 + c] = u1;
    }
    __builtin_amdgcn_s_waitcnt(0xc07f);   // lgkmcnt(0)
    __builtin_amdgcn_wave_barrier();
    bf16x8 pa = *reinterpret_cast<const bf16x8*>(pm + c * 32 + quad * 8);
    __builtin_amdgcn_s_setprio(1);
    for (int dt = 0; dt < 5; dt++)
      accd[dt] = __builtin_amdgcn_mfma_f32_16x16x32_bf16(pa, bv[dt], accd[dt], 0, 0, 0);
    __builtin_amdgcn_s_setprio(0);
  }

  if (wave == 1){
    for (int dt = 0; dt < 5; dt++)
      for (int rr = 0; rr < 4; rr++) accS[dt][lane][rr] = accd[dt][rr];
    for (int rr = 0; rr < 4; rr++) lsumS[lane][rr] = lsum[rr];
  }
  __syncthreads();
  if (wave == 0){
    for (int dt = 0; dt < 5; dt++)
      for (int rr = 0; rr < 4; rr++) accd[dt][rr] += accS[dt][lane][rr];
    for (int rr = 0; rr < 4; rr++) lsum[rr] += lsumS[lane][rr];

    float inv[4];
    for (int rr = 0; rr < 4; rr++){
      float rs = lsum[rr];
      rs += __shfl_xor(rs, 1);
      rs += __shfl_xor(rs, 2);
      rs += __shfl_xor(rs, 4);
      rs += __shfl_xor(rs, 8);
      inv[rr] = (rs > 0.f) ? 1.0f / rs : 0.f;
    }
    for (int dt = 0; dt < 5; dt++)
      for (int rr = 0; rr < 4; rr++){
        int t = t0 + quad * 4 + rr;
        Oh[(size_t)t * HIDDEN + h * HD + dt * 16 + c] = f2bf(accd[dt][rr] * inv[rr]);
      }
  }
}

extern "C" void kernel_launch(void* const* d_in, const int* in_sizes, int n_in,
                              void* d_out, int out_size, void* d_ws, size_t ws_size,
                              hipStream_t stream)
{
  const void* X    = d_in[0];
  const void* rope = d_in[1];
  const int*  seg  = (const int*)d_in[2];
  const void* Wq   = d_in[3];
  const void* bq   = d_in[4];
  const void* Wp   = d_in[5];
  const void* bp   = d_in[6];

  char* ws = (char*)d_ws;
  size_t off = 0;
  auto alloc = [&](size_t bytes){ void* p = ws + off; off += (bytes + 255) & ~(size_t)255; return p; };
  int*    flag = (int*)alloc(4);
  int*    segS = (int*)alloc(TSEQ * 4);
  int*    segE = (int*)alloc(TSEQ * 4);
  ushort* Xb   = (ushort*)alloc((size_t)TSEQ * HIDDEN * 2);          // 5.24 MB (aliased by Oh later)
  ushort* Qh   = (ushort*)alloc((size_t)NH * TSEQ * HDP * 2);        // 6.29 MB
  ushort* Kh   = (ushort*)alloc((size_t)NH * TSEQ * HDP * 2);        // 6.29 MB
  ushort* Vt   = (ushort*)alloc((size_t)NH * HD * TSEQ * 2);         // 5.24 MB
  ushort* WT1  = (ushort*)alloc((size_t)3 * HIDDEN * HIDDEN * 2);    // 9.83 MB
  ushort* WT2  = (ushort*)alloc((size_t)HIDDEN * HIDDEN * 2);        // 3.28 MB
  ushort* qkv  = (ushort*)alloc((size_t)TSEQ * 3 * HIDDEN * 2);      // 15.73 MB
  ushort* Oh   = Xb;   // Xb dead after gemm<0>; attn writes Oh afterwards

  misc_k<<<9, 256, 0, stream>>>((const ushort*)X, seg, flag, segS, segE);
  prep_k<<<8960, 256, 0, stream>>>(flag, X, Wq, Wp, Xb, WT1, WT2);
  gemm_k<0,128><<<dim3(30, 16), 256, 0, stream>>>(Xb, WT1, bq, HIDDEN, 3 * HIDDEN, flag, qkv);
  reshape_k<<<2560, 256, 0, stream>>>(flag, qkv, rope, Qh, Kh, Vt);
  attn_k<<<2048, 128, 0, stream>>>(Qh, Kh, Vt, seg, segS, segE, Oh);
  gemm_k<1,64><<<dim3(20, 16), 256, 0, stream>>>(Oh, WT2, bp, HIDDEN, HIDDEN, flag, d_out);
}

// Round 3
// 181.689 us; speedup vs baseline: 1.0065x; 1.0065x over previous
//
#include <hip/hip_runtime.h>
#include <math.h>

#define TSEQ 2048
#define HIDDEN 1280
#define NH 16
#define HD 80
#define HDP 96
#define ATTN_SCALE 0.11180339887498949f

typedef __bf16 bf16x8 __attribute__((ext_vector_type(8)));
typedef float f32x4 __attribute__((ext_vector_type(4)));

__device__ inline float bf2f(ushort u){ union { unsigned int u; float f; } v; v.u = ((unsigned int)u) << 16; return v.f; }
__device__ inline ushort f2bf(float f){
  union { float f; unsigned int u; } v; v.f = f;
  unsigned int u = v.u;
  return (ushort)((u + 0x7fffu + ((u >> 16) & 1u)) >> 16);
}
__device__ inline float ldin(const void* p, size_t i, bool f32){
  return f32 ? ((const float*)p)[i] : bf2f(((const ushort*)p)[i]);
}
// async global->LDS, 16B per lane; lds base must be wave-uniform, lane i lands at base + i*16B
__device__ inline void gl_lds16(const ushort* gp, ushort* lds_base){
  __builtin_amdgcn_global_load_lds(
      (const __attribute__((address_space(1))) unsigned int*)gp,
      (__attribute__((address_space(3))) unsigned int*)lds_base, 16, 0, 0);
}

// ---------------- misc: dtype detect (block 0) + segment bounds (blocks 1..8) ----------------
__global__ void misc_k(const ushort* __restrict__ X, const int* __restrict__ seg,
                       int* __restrict__ flag, int* __restrict__ segS, int* __restrict__ segE){
  int b = blockIdx.x, tid = threadIdx.x;
  if (b == 0){
    int insane = 0;
    for (int i = tid; i < 2048; i += 256){
      ushort u = X[i];
      int e = (u >> 7) & 0xFF;
      int m = u & 0x7F;
      bool bad = (e >= 0xC0) || (e != 0 && e <= 0x30) || (e == 0 && m != 0);
      if (bad) insane++;
    }
    __shared__ int s[256];
    s[tid] = insane; __syncthreads();
    for (int st = 128; st > 0; st >>= 1){ if (tid < st) s[tid] += s[tid + st]; __syncthreads(); }
    if (tid == 0) *flag = (s[0] > 128) ? 1 : 0;   // 1 => fp32 inputs
  } else {
    int t = (b - 1) * 256 + tid;
    int id = seg[t];
    int lo = 0, hi = TSEQ;
    while (lo < hi){ int mid = (lo + hi) >> 1; if (seg[mid] < id) lo = mid + 1; else hi = mid; }
    segS[t] = lo;
    lo = 0; hi = TSEQ;
    while (lo < hi){ int mid = (lo + hi) >> 1; if (seg[mid] <= id) lo = mid + 1; else hi = mid; }
    segE[t] = lo;
  }
}

// ---------------- prep: X convert (blocks 0..2559) + WT1 (2560..7359) + WT2 (7360..8959) ----
__global__ void prep_k(const int* __restrict__ flag, const void* __restrict__ X,
                       const void* __restrict__ Wq, const void* __restrict__ Wp,
                       ushort* __restrict__ Xb, ushort* __restrict__ WT1, ushort* __restrict__ WT2){
  __shared__ ushort tile[32][33];
  const bool f32 = (*flag != 0);
  int b = blockIdx.x, tid = threadIdx.x;
  if (b < 2560){
    int i = (b * 256 + tid) * 4;
    ushort o[4];
    if (f32){
      float4 v = *reinterpret_cast<const float4*>((const float*)X + i);
      o[0] = f2bf(v.x); o[1] = f2bf(v.y); o[2] = f2bf(v.z); o[3] = f2bf(v.w);
    } else {
      *reinterpret_cast<ushort4*>(o) = *reinterpret_cast<const ushort4*>((const ushort*)X + i);
    }
    *reinterpret_cast<ushort4*>(Xb + i) = *reinterpret_cast<ushort4*>(o);
    return;
  }
  const void* in; ushort* out; int rows, cols, tb;
  if (b < 7360){ tb = b - 2560; in = Wq; out = WT1; rows = HIDDEN; cols = 3 * HIDDEN; }
  else         { tb = b - 7360; in = Wp; out = WT2; rows = HIDDEN; cols = HIDDEN; }
  int tpr = cols / 32;
  int bx = (tb % tpr) * 32, by = (tb / tpr) * 32;
  int tx = tid & 31, ty = tid >> 5;
  for (int i = ty; i < 32; i += 8){
    size_t idx = (size_t)(by + i) * cols + bx + tx;
    tile[i][tx] = f32 ? f2bf(((const float*)in)[idx]) : ((const ushort*)in)[idx];
  }
  __syncthreads();
  for (int i = ty; i < 32; i += 8)
    out[(size_t)(bx + i) * rows + by + tx] = tile[tx][i];
}

// ---------------- GEMM: C[M,N] = A[M,K] @ BT[N,K]^T + bias ----------------
// BK=64, dbuf LDS, global_load_lds staging gated by raw vmcnt(N) barriers (AITER-style),
// 8-group XOR bank swizzle. XCD-bijective block swizzle (nwg % 8 == 0 for both launches).
// MODE 0: bf16 out. MODE 1: out dtype per flag. BN: 128 or 64.
template<int MODE, int BN>
__launch_bounds__(256, 2)
__global__ void gemm_k(const ushort* __restrict__ A, const ushort* __restrict__ BT,
                       const void* __restrict__ bias, int K, int N,
                       const int* __restrict__ flagp, void* __restrict__ out)
{
  constexpr int NFJ = (BN == 128) ? 4 : 2;   // n-fragments per wave
  constexpr int BDM = (BN == 128) ? 4 : 2;   // B DMAs per wave per tile (8 rows each)
  __shared__ __align__(16) ushort As[2][128 * 64];
  __shared__ __align__(16) ushort Bs[2][BN * 64];
  const int tid = threadIdx.x;
  const int wave = tid >> 6, lane = tid & 63;
  const int quad = lane >> 4, c = lane & 15;

  // XCD-bijective swizzle: contiguous chunk of linear ids per XCD -> A-panel L2 reuse
  const int lin = blockIdx.y * gridDim.x + blockIdx.x;
  const int cpx = (gridDim.x * gridDim.y) >> 3;
  const int nid = (lin & 7) * cpx + (lin >> 3);
  const int bx = nid % gridDim.x, by = nid / gridDim.x;

  const int m0 = by * 128, n0 = bx * BN;
  const int wm = (wave & 1) * 64, wn = (wave >> 1) * (BN / 2);

  f32x4 acc[4][NFJ];
  for (int i = 0; i < 4; i++) for (int j = 0; j < NFJ; j++) acc[i][j] = (f32x4){0.f,0.f,0.f,0.f};

  const int drow = lane >> 3;
  const int dcg  = lane & 7;
  const int L8   = ((dcg ^ drow) * 8);
  const int brow = wave * (BN / 4);          // B staging row base for this wave
  const ushort* Ab = A  + (size_t)(m0 + wave * 32 + drow) * K + L8;
  const ushort* Bb = BT + (size_t)(n0 + brow + drow) * K + L8;
  const size_t row8 = (size_t)8 * K;
  const int woffA = wave * 32 * 64;
  const int woffB = brow * 64;

  // prologue: stage tile 0 into buffer 0 (4+BDM DMAs per wave)
  for (int d = 0; d < 4; d++)   gl_lds16(Ab + d * row8, As[0] + woffA + d * 512);
  for (int d = 0; d < BDM; d++) gl_lds16(Bb + d * row8, Bs[0] + woffB + d * 512);

  int cur = 0;
  for (int k0 = 0; k0 < K; k0 += 64){
    if (k0 + 64 < K){
      int nxt = cur ^ 1;
      for (int d = 0; d < 4; d++)   gl_lds16(Ab + d * row8 + k0 + 64, As[nxt] + woffA + d * 512);
      for (int d = 0; d < BDM; d++) gl_lds16(Bb + d * row8 + k0 + 64, Bs[nxt] + woffB + d * 512);
      // wait only for the PREVIOUS tile's DMAs; the fresh ones stay in flight
      if constexpr (BN == 128)
        asm volatile("s_waitcnt vmcnt(8)\ns_barrier" ::: "memory");
      else
        asm volatile("s_waitcnt vmcnt(6)\ns_barrier" ::: "memory");
    } else {
      asm volatile("s_waitcnt vmcnt(0)\ns_barrier" ::: "memory");
    }
    const ushort* Ac = As[cur];
    const ushort* Bc = Bs[cur];
    for (int ks = 0; ks < 2; ks++){
      const int pq8 = (((ks * 4 + quad) ^ (c & 7)) * 8);
      bf16x8 af[4], bfv[NFJ];
      for (int i = 0; i < 4; i++)   af[i]  = *reinterpret_cast<const bf16x8*>(&Ac[(wm + i*16 + c) * 64 + pq8]);
      for (int j = 0; j < NFJ; j++) bfv[j] = *reinterpret_cast<const bf16x8*>(&Bc[(wn + j*16 + c) * 64 + pq8]);
      for (int i = 0; i < 4; i++)
        for (int j = 0; j < NFJ; j++)
          acc[i][j] = __builtin_amdgcn_mfma_f32_16x16x32_bf16(af[i], bfv[j], acc[i][j], 0, 0, 0);
    }
    // all waves must finish reading 'cur' before next iteration's DMA overwrites it
    asm volatile("s_waitcnt lgkmcnt(0)\ns_barrier" ::: "memory");
    cur ^= 1;
  }

  const bool f32 = (*flagp != 0);

  for (int j = 0; j < NFJ; j++){
    int n = n0 + wn + j*16 + c;
    float bv = ldin(bias, n, f32);
    for (int i = 0; i < 4; i++){
      int mbase = m0 + wm + i*16 + quad*4;
      for (int rr = 0; rr < 4; rr++){
        float v = acc[i][j][rr] + bv;
        size_t idx = (size_t)(mbase + rr) * N + n;
        if (MODE == 1 && f32) ((float*)out)[idx] = v;
        else                  ((ushort*)out)[idx] = f2bf(v);
      }
    }
  }
}

// ---------------- reshape: RoPE Q/K (blocks 0..2047) + V transpose (2048..2559) ------------
__global__ void reshape_k(const int* __restrict__ flag, const ushort* __restrict__ qkv,
                          const void* __restrict__ rope,
                          ushort* __restrict__ Qh, ushort* __restrict__ Kh, ushort* __restrict__ Vt){
  __shared__ __align__(16) ushort shm[5632];
  int b = blockIdx.x, tid = threadIdx.x;
  if (b < 2048){
    ushort* row = shm;           // 3840
    ushort* rrow = shm + 3840;   // 40
    int t = b;
    for (int i = tid; i < 480; i += 256)
      *reinterpret_cast<uint4*>(&row[i * 8]) = *reinterpret_cast<const uint4*>(qkv + (size_t)t * 3840 + i * 8);
    if (tid < 40)
      rrow[tid] = f2bf(ldin(rope, t * 40 + tid, *flag != 0));
    __syncthreads();
    int w = tid;
    if (w < 160){
      int part = w / 80;                 // 0=Q, 1=K
      int hw = w - part * 80;
      int h = hw / 5, dr0 = (hw % 5) * 8;
      const ushort* src = &row[part * HIDDEN + h * HD];
      ushort* dst = (part ? Kh : Qh) + ((size_t)h * TSEQ + t) * HDP;
      ushort o0[8], o1[8];
      for (int d = 0; d < 8; d++){
        float th = bf2f(rrow[dr0 + d]);
        float cs, sn;
        __sincosf(th, &sn, &cs);         // v_sin_f32/v_cos_f32 — theta ~ N(0,1), fast path exact to bf16
        float xr = bf2f(src[dr0 + d]);
        float xi = bf2f(src[dr0 + d + 40]);
        o0[d] = f2bf(xr * cs - xi * sn);
        o1[d] = f2bf(xr * sn + xi * cs);
      }
      *reinterpret_cast<uint4*>(dst + dr0)      = *reinterpret_cast<uint4*>(o0);
      *reinterpret_cast<uint4*>(dst + dr0 + 40) = *reinterpret_cast<uint4*>(o1);
    } else if (w < 224){
      int idx = w - 160;                 // 64 items: {Q,K} x 16h x 2seg
      int part = idx >> 5;
      int h = (idx & 31) >> 1, sg = idx & 1;
      ushort* dst = (part ? Kh : Qh) + ((size_t)h * TSEQ + t) * HDP + 80 + sg * 8;
      uint4 z = {0, 0, 0, 0};
      *reinterpret_cast<uint4*>(dst) = z;
    }
  } else {
    int vb = b - 2048;
    int h = vb & 15, t0 = (vb >> 4) * 64;
    const ushort* src = qkv + 2 * HIDDEN + h * HD;
    // tile[64][88]
    for (int w = tid; w < 640; w += 256){
      int r = w / 10, cc = (w % 10) * 8;
      *reinterpret_cast<uint4*>(&shm[r * 88 + cc]) = *reinterpret_cast<const uint4*>(src + (size_t)(t0 + r) * 3840 + cc);
    }
    __syncthreads();
    for (int w = tid; w < 320; w += 256){
      int d = w >> 2, sg = (w & 3) * 16;
      ushort tmp[16];
      for (int i = 0; i < 16; i++) tmp[i] = shm[(sg + i) * 88 + d];
      ushort* dst = Vt + ((size_t)h * HD + d) * TSEQ + t0 + sg;
      *reinterpret_cast<uint4*>(dst)     = *reinterpret_cast<uint4*>(tmp);
      *reinterpret_cast<uint4*>(dst + 8) = *reinterpret_cast<uint4*>(tmp + 8);
    }
  }
}

// ---------------- attention: 16 q/tile, 2 waves split the k-range (additive partials) ------
// VGPR discipline: V fragments (40) issued first — their latency must hide under exp+LDS;
// K fragments loaded in pairs (16 live) interleaved with QK MFMAs. Peak live ~128 = budget.
__launch_bounds__(128, 4)
__global__ void attn_k(const ushort* __restrict__ Qh, const ushort* __restrict__ Kh,
                       const ushort* __restrict__ Vt, const int* __restrict__ seg,
                       const int* __restrict__ segS, const int* __restrict__ segE,
                       ushort* __restrict__ Oh)
{
  __shared__ __align__(16) ushort Pm[2][2][512];   // [wave][dbuf][16*32]
  __shared__ float accS[5][64][4];                 // wave1 partial O
  __shared__ float lsumS[64][4];                   // wave1 partial l
  int tid = threadIdx.x;
  int wave = tid >> 6, lane = tid & 63;
  int quad = lane >> 4, c = lane & 15;
  int b = blockIdx.x;
  int xcd = b & 7, slot = b >> 3;
  int h = slot & 15;
  int t0 = (xcd * 16 + (slot >> 4)) * 16;

  const ushort* Qb = Qh + (size_t)h * TSEQ * HDP;
  const ushort* Kb = Kh + (size_t)h * TSEQ * HDP;
  const ushort* Vb = Vt + (size_t)h * HD * TSEQ;

  bf16x8 aq[3];
  for (int i = 0; i < 3; i++)
    aq[i] = *reinterpret_cast<const bf16x8*>(Qb + (size_t)(t0 + c) * HDP + i * 32 + quad * 8);

  int segq[4];
  for (int rr = 0; rr < 4; rr++) segq[rr] = seg[t0 + quad * 4 + rr];

  int kstart = segS[t0] & ~31;
  int kend   = segE[t0 + 15];

  float lsum[4] = {0.f, 0.f, 0.f, 0.f};
  f32x4 accd[5];
  for (int dt = 0; dt < 5; dt++) accd[dt] = (f32x4){0.f,0.f,0.f,0.f};

  for (int kt = kstart + wave * 32; kt < kend; kt += 64){
    ushort* pm = &Pm[wave][(kt >> 6) & 1][0];
    const ushort* Kp = Kb + (size_t)(kt + c) * HDP + quad * 8;
    const ushort* Vp = Vb + (size_t)c * TSEQ + kt + quad * 8;

    // early-issue V fragment loads (independent of everything until PV)
    bf16x8 bv0 = *reinterpret_cast<const bf16x8*>(Vp);
    bf16x8 bv1 = *reinterpret_cast<const bf16x8*>(Vp + 16 * TSEQ);
    bf16x8 bv2 = *reinterpret_cast<const bf16x8*>(Vp + 32 * TSEQ);
    bf16x8 bv3 = *reinterpret_cast<const bf16x8*>(Vp + 48 * TSEQ);
    bf16x8 bv4 = *reinterpret_cast<const bf16x8*>(Vp + 64 * TSEQ);

    f32x4 s0 = (f32x4){0.f,0.f,0.f,0.f}, s1 = (f32x4){0.f,0.f,0.f,0.f};
    for (int i = 0; i < 3; i++){
      bf16x8 bk0 = *reinterpret_cast<const bf16x8*>(Kp + i * 32);
      bf16x8 bk1 = *reinterpret_cast<const bf16x8*>(Kp + 16 * HDP + i * 32);
      __builtin_amdgcn_s_setprio(1);
      s0 = __builtin_amdgcn_mfma_f32_16x16x32_bf16(aq[i], bk0, s0, 0, 0, 0);
      s1 = __builtin_amdgcn_mfma_f32_16x16x32_bf16(aq[i], bk1, s1, 0, 0, 0);
      __builtin_amdgcn_s_setprio(0);
    }

    int segk0 = seg[kt + c];
    int segk1 = seg[kt + 16 + c];
    for (int rr = 0; rr < 4; rr++){
      bool ok0 = (segq[rr] == segk0);
      bool ok1 = (segq[rr] == segk1);
      float e0 = ok0 ? __expf(fminf(s0[rr] * ATTN_SCALE, 30.f)) : 0.f;
      float e1 = ok1 ? __expf(fminf(s1[rr] * ATTN_SCALE, 30.f)) : 0.f;
      ushort u0 = f2bf(e0), u1 = f2bf(e1);
      lsum[rr] += bf2f(u0) + bf2f(u1);
      pm[(quad * 4 + rr) * 32 + c]      = u0;
      pm[(quad * 4 + rr) * 32 + 16 + c] = u1;
    }
    __builtin_amdgcn_s_waitcnt(0xc07f);   // lgkmcnt(0)
    __builtin_amdgcn_wave_barrier();
    bf16x8 pa = *reinterpret_cast<const bf16x8*>(pm + c * 32 + quad * 8);
    __builtin_amdgcn_s_setprio(1);
    accd[0] = __builtin_amdgcn_mfma_f32_16x16x32_bf16(pa, bv0, accd[0], 0, 0, 0);
    accd[1] = __builtin_amdgcn_mfma_f32_16x16x32_bf16(pa, bv1, accd[1], 0, 0, 0);
    accd[2] = __builtin_amdgcn_mfma_f32_16x16x32_bf16(pa, bv2, accd[2], 0, 0, 0);
    accd[3] = __builtin_amdgcn_mfma_f32_16x16x32_bf16(pa, bv3, accd[3], 0, 0, 0);
    accd[4] = __builtin_amdgcn_mfma_f32_16x16x32_bf16(pa, bv4, accd[4], 0, 0, 0);
    __builtin_amdgcn_s_setprio(0);
  }

  if (wave == 1){
    for (int dt = 0; dt < 5; dt++)
      for (int rr = 0; rr < 4; rr++) accS[dt][lane][rr] = accd[dt][rr];
    for (int rr = 0; rr < 4; rr++) lsumS[lane][rr] = lsum[rr];
  }
  __syncthreads();
  if (wave == 0){
    for (int dt = 0; dt < 5; dt++)
      for (int rr = 0; rr < 4; rr++) accd[dt][rr] += accS[dt][lane][rr];
    for (int rr = 0; rr < 4; rr++) lsum[rr] += lsumS[lane][rr];

    float inv[4];
    for (int rr = 0; rr < 4; rr++){
      float rs = lsum[rr];
      rs += __shfl_xor(rs, 1);
      rs += __shfl_xor(rs, 2);
      rs += __shfl_xor(rs, 4);
      rs += __shfl_xor(rs, 8);
      inv[rr] = (rs > 0.f) ? 1.0f / rs : 0.f;
    }
    for (int dt = 0; dt < 5; dt++)
      for (int rr = 0; rr < 4; rr++){
        int t = t0 + quad * 4 + rr;
        Oh[(size_t)t * HIDDEN + h * HD + dt * 16 + c] = f2bf(accd[dt][rr] * inv[rr]);
      }
  }
}

extern "C" void kernel_launch(void* const* d_in, const int* in_sizes, int n_in,
                              void* d_out, int out_size, void* d_ws, size_t ws_size,
                              hipStream_t stream)
{
  const void* X    = d_in[0];
  const void* rope = d_in[1];
  const int*  seg  = (const int*)d_in[2];
  const void* Wq   = d_in[3];
  const void* bq   = d_in[4];
  const void* Wp   = d_in[5];
  const void* bp   = d_in[6];

  char* ws = (char*)d_ws;
  size_t off = 0;
  auto alloc = [&](size_t bytes){ void* p = ws + off; off += (bytes + 255) & ~(size_t)255; return p; };
  int*    flag = (int*)alloc(4);
  int*    segS = (int*)alloc(TSEQ * 4);
  int*    segE = (int*)alloc(TSEQ * 4);
  ushort* Xb   = (ushort*)alloc((size_t)TSEQ * HIDDEN * 2);          // 5.24 MB (aliased by Oh later)
  ushort* Qh   = (ushort*)alloc((size_t)NH * TSEQ * HDP * 2);        // 6.29 MB
  ushort* Kh   = (ushort*)alloc((size_t)NH * TSEQ * HDP * 2);        // 6.29 MB
  ushort* Vt   = (ushort*)alloc((size_t)NH * HD * TSEQ * 2);         // 5.24 MB
  ushort* WT1  = (ushort*)alloc((size_t)3 * HIDDEN * HIDDEN * 2);    // 9.83 MB
  ushort* WT2  = (ushort*)alloc((size_t)HIDDEN * HIDDEN * 2);        // 3.28 MB
  ushort* qkv  = (ushort*)alloc((size_t)TSEQ * 3 * HIDDEN * 2);      // 15.73 MB
  ushort* Oh   = Xb;   // Xb dead after gemm<0>; attn writes Oh afterwards

  misc_k<<<9, 256, 0, stream>>>((const ushort*)X, seg, flag, segS, segE);
  prep_k<<<8960, 256, 0, stream>>>(flag, X, Wq, Wp, Xb, WT1, WT2);
  gemm_k<0,128><<<dim3(30, 16), 256, 0, stream>>>(Xb, WT1, bq, HIDDEN, 3 * HIDDEN, flag, qkv);
  reshape_k<<<2560, 256, 0, stream>>>(flag, qkv, rope, Qh, Kh, Vt);
  attn_k<<<2048, 128, 0, stream>>>(Qh, Kh, Vt, seg, segS, segE, Oh);
  gemm_k<1,64><<<dim3(20, 16), 256, 0, stream>>>(Oh, WT2, bp, HIDDEN, HIDDEN, flag, d_out);
}

// Round 5
// 176.656 us; speedup vs baseline: 1.0352x; 1.0285x over previous
//
#include <hip/hip_runtime.h>
#include <math.h>

#define TSEQ 2048
#define HIDDEN 1280
#define NH 16
#define HD 80
#define HDP 96
#define ATTN_SCALE 0.11180339887498949f

typedef __bf16 bf16x8 __attribute__((ext_vector_type(8)));
typedef float f32x4 __attribute__((ext_vector_type(4)));

__device__ inline float bf2f(ushort u){ union { unsigned int u; float f; } v; v.u = ((unsigned int)u) << 16; return v.f; }
__device__ inline ushort f2bf(float f){
  union { float f; unsigned int u; } v; v.f = f;
  unsigned int u = v.u;
  return (ushort)((u + 0x7fffu + ((u >> 16) & 1u)) >> 16);
}
__device__ inline float ldin(const void* p, size_t i, bool f32){
  return f32 ? ((const float*)p)[i] : bf2f(((const ushort*)p)[i]);
}
// async global->LDS, 16B per lane; lds base must be wave-uniform, lane i lands at base + i*16B
__device__ inline void gl_lds16(const ushort* gp, ushort* lds_base){
  __builtin_amdgcn_global_load_lds(
      (const __attribute__((address_space(1))) unsigned int*)gp,
      (__attribute__((address_space(3))) unsigned int*)lds_base, 16, 0, 0);
}

// ---------------- misc: dtype detect (block 0) + segment bounds (blocks 1..8) ----------------
__global__ void misc_k(const ushort* __restrict__ X, const int* __restrict__ seg,
                       int* __restrict__ flag, int* __restrict__ segS, int* __restrict__ segE){
  int b = blockIdx.x, tid = threadIdx.x;
  if (b == 0){
    int insane = 0;
    for (int i = tid; i < 2048; i += 256){
      ushort u = X[i];
      int e = (u >> 7) & 0xFF;
      int m = u & 0x7F;
      bool bad = (e >= 0xC0) || (e != 0 && e <= 0x30) || (e == 0 && m != 0);
      if (bad) insane++;
    }
    __shared__ int s[256];
    s[tid] = insane; __syncthreads();
    for (int st = 128; st > 0; st >>= 1){ if (tid < st) s[tid] += s[tid + st]; __syncthreads(); }
    if (tid == 0) *flag = (s[0] > 128) ? 1 : 0;   // 1 => fp32 inputs
  } else {
    int t = (b - 1) * 256 + tid;
    int id = seg[t];
    int lo = 0, hi = TSEQ;
    while (lo < hi){ int mid = (lo + hi) >> 1; if (seg[mid] < id) lo = mid + 1; else hi = mid; }
    segS[t] = lo;
    lo = 0; hi = TSEQ;
    while (lo < hi){ int mid = (lo + hi) >> 1; if (seg[mid] <= id) lo = mid + 1; else hi = mid; }
    segE[t] = lo;
  }
}

// ---------------- prep: X convert (blocks 0..1279) + WT1 (1280..2479) + WT2 (2480..2879) ----
// 64x64 transpose tiles, 16B global loads AND stores. LDS [64][64] with XOR swizzle
// col' = col ^ (8*((row>>3)&7)): b128 writes hit the 8-cycle floor evenly; scalar reads
// land 2 lanes/bank (free).
__global__ void prep_k(const int* __restrict__ flag, const void* __restrict__ X,
                       const void* __restrict__ Wq, const void* __restrict__ Wp,
                       ushort* __restrict__ Xb, ushort* __restrict__ WT1, ushort* __restrict__ WT2){
  __shared__ __align__(16) ushort tile[64][64];
  const bool f32 = (*flag != 0);
  int b = blockIdx.x, tid = threadIdx.x;
  if (b < 1280){
    size_t i = ((size_t)b * 256 + tid) * 8;
    ushort o[8];
    if (f32){
      float4 v0 = *reinterpret_cast<const float4*>((const float*)X + i);
      float4 v1 = *reinterpret_cast<const float4*>((const float*)X + i + 4);
      o[0] = f2bf(v0.x); o[1] = f2bf(v0.y); o[2] = f2bf(v0.z); o[3] = f2bf(v0.w);
      o[4] = f2bf(v1.x); o[5] = f2bf(v1.y); o[6] = f2bf(v1.z); o[7] = f2bf(v1.w);
    } else {
      *reinterpret_cast<uint4*>(o) = *reinterpret_cast<const uint4*>((const ushort*)X + i);
    }
    *reinterpret_cast<uint4*>(Xb + i) = *reinterpret_cast<uint4*>(o);
    return;
  }
  const void* in; ushort* out; int rows, cols, tb;
  if (b < 2480){ tb = b - 1280; in = Wq; out = WT1; rows = HIDDEN; cols = 3 * HIDDEN; }
  else         { tb = b - 2480; in = Wp; out = WT2; rows = HIDDEN; cols = HIDDEN; }
  const int tpr = cols / 64;
  const int bx = (tb % tpr) * 64, by = (tb / tpr) * 64;   // bx: N-offset, by: K-offset
  const int r = tid >> 3;              // 0..31
  const int g = (tid & 7) * 8;         // 0,8,...,56
  // load: rows r and r+32, 8 consecutive cols at g; write swizzled into LDS
  for (int rr = r; rr < 64; rr += 32){
    const int sw = (g ^ (8 * ((rr >> 3) & 7)));
    ushort o[8];
    if (f32){
      const float* p = (const float*)in + (size_t)(by + rr) * cols + bx + g;
      float4 v0 = *reinterpret_cast<const float4*>(p);
      float4 v1 = *reinterpret_cast<const float4*>(p + 4);
      o[0] = f2bf(v0.x); o[1] = f2bf(v0.y); o[2] = f2bf(v0.z); o[3] = f2bf(v0.w);
      o[4] = f2bf(v1.x); o[5] = f2bf(v1.y); o[6] = f2bf(v1.z); o[7] = f2bf(v1.w);
    } else {
      *reinterpret_cast<uint4*>(o) =
        *reinterpret_cast<const uint4*>((const ushort*)in + (size_t)(by + rr) * cols + bx + g);
    }
    *reinterpret_cast<uint4*>(&tile[rr][sw]) = *reinterpret_cast<uint4*>(o);
  }
  __syncthreads();
  // store: output row n = bx+rr, k-chunk by+g..by+g+7 ; gather column rr from LDS
  const int gg = tid & 7;
  for (int rr = r; rr < 64; rr += 32){
    ushort o[8];
    for (int i = 0; i < 8; i++) o[i] = tile[g + i][rr ^ (8 * gg)];
    *reinterpret_cast<uint4*>(out + (size_t)(bx + rr) * rows + by + g) = *reinterpret_cast<uint4*>(o);
  }
}

// ---------------- GEMM: C[M,N] = A[M,K] @ BT[N,K]^T + bias ----------------
// BK=64, dbuf LDS, global_load_lds staging gated by raw vmcnt(N) barriers (AITER-style),
// 8-group XOR bank swizzle. XCD-bijective block swizzle (nwg % 8 == 0 for both launches).
// MODE 0: bf16 out. MODE 1: out dtype per flag. BN: 128 or 64.
template<int MODE, int BN>
__launch_bounds__(256, 2)
__global__ void gemm_k(const ushort* __restrict__ A, const ushort* __restrict__ BT,
                       const void* __restrict__ bias, int K, int N,
                       const int* __restrict__ flagp, void* __restrict__ out)
{
  constexpr int NFJ = (BN == 128) ? 4 : 2;   // n-fragments per wave
  constexpr int BDM = (BN == 128) ? 4 : 2;   // B DMAs per wave per tile (8 rows each)
  __shared__ __align__(16) ushort As[2][128 * 64];
  __shared__ __align__(16) ushort Bs[2][BN * 64];
  const int tid = threadIdx.x;
  const int wave = tid >> 6, lane = tid & 63;
  const int quad = lane >> 4, c = lane & 15;

  // XCD-bijective swizzle: contiguous chunk of linear ids per XCD -> A-panel L2 reuse
  const int lin = blockIdx.y * gridDim.x + blockIdx.x;
  const int cpx = (gridDim.x * gridDim.y) >> 3;
  const int nid = (lin & 7) * cpx + (lin >> 3);
  const int bx = nid % gridDim.x, by = nid / gridDim.x;

  const int m0 = by * 128, n0 = bx * BN;
  const int wm = (wave & 1) * 64, wn = (wave >> 1) * (BN / 2);

  f32x4 acc[4][NFJ];
  for (int i = 0; i < 4; i++) for (int j = 0; j < NFJ; j++) acc[i][j] = (f32x4){0.f,0.f,0.f,0.f};

  const int drow = lane >> 3;
  const int dcg  = lane & 7;
  const int L8   = ((dcg ^ drow) * 8);
  const int brow = wave * (BN / 4);          // B staging row base for this wave
  const ushort* Ab = A  + (size_t)(m0 + wave * 32 + drow) * K + L8;
  const ushort* Bb = BT + (size_t)(n0 + brow + drow) * K + L8;
  const size_t row8 = (size_t)8 * K;
  const int woffA = wave * 32 * 64;
  const int woffB = brow * 64;

  // prologue: stage tile 0 into buffer 0 (4+BDM DMAs per wave)
  for (int d = 0; d < 4; d++)   gl_lds16(Ab + d * row8, As[0] + woffA + d * 512);
  for (int d = 0; d < BDM; d++) gl_lds16(Bb + d * row8, Bs[0] + woffB + d * 512);

  int cur = 0;
  for (int k0 = 0; k0 < K; k0 += 64){
    if (k0 + 64 < K){
      int nxt = cur ^ 1;
      for (int d = 0; d < 4; d++)   gl_lds16(Ab + d * row8 + k0 + 64, As[nxt] + woffA + d * 512);
      for (int d = 0; d < BDM; d++) gl_lds16(Bb + d * row8 + k0 + 64, Bs[nxt] + woffB + d * 512);
      // wait only for the PREVIOUS tile's DMAs; the fresh ones stay in flight
      if constexpr (BN == 128)
        asm volatile("s_waitcnt vmcnt(8)\ns_barrier" ::: "memory");
      else
        asm volatile("s_waitcnt vmcnt(6)\ns_barrier" ::: "memory");
    } else {
      asm volatile("s_waitcnt vmcnt(0)\ns_barrier" ::: "memory");
    }
    const ushort* Ac = As[cur];
    const ushort* Bc = Bs[cur];
    for (int ks = 0; ks < 2; ks++){
      const int pq8 = (((ks * 4 + quad) ^ (c & 7)) * 8);
      bf16x8 af[4], bfv[NFJ];
      for (int i = 0; i < 4; i++)   af[i]  = *reinterpret_cast<const bf16x8*>(&Ac[(wm + i*16 + c) * 64 + pq8]);
      for (int j = 0; j < NFJ; j++) bfv[j] = *reinterpret_cast<const bf16x8*>(&Bc[(wn + j*16 + c) * 64 + pq8]);
      for (int i = 0; i < 4; i++)
        for (int j = 0; j < NFJ; j++)
          acc[i][j] = __builtin_amdgcn_mfma_f32_16x16x32_bf16(af[i], bfv[j], acc[i][j], 0, 0, 0);
    }
    // all waves must finish reading 'cur' before next iteration's DMA overwrites it
    asm volatile("s_waitcnt lgkmcnt(0)\ns_barrier" ::: "memory");
    cur ^= 1;
  }

  const bool f32 = (*flagp != 0);

  for (int j = 0; j < NFJ; j++){
    int n = n0 + wn + j*16 + c;
    float bv = ldin(bias, n, f32);
    for (int i = 0; i < 4; i++){
      int mbase = m0 + wm + i*16 + quad*4;
      for (int rr = 0; rr < 4; rr++){
        float v = acc[i][j][rr] + bv;
        size_t idx = (size_t)(mbase + rr) * N + n;
        if (MODE == 1 && f32) ((float*)out)[idx] = v;
        else                  ((ushort*)out)[idx] = f2bf(v);
      }
    }
  }
}

// ---------------- reshape: RoPE Q/K (blocks 0..2047) + V transpose (2048..2559) ------------
__global__ void reshape_k(const int* __restrict__ flag, const ushort* __restrict__ qkv,
                          const void* __restrict__ rope,
                          ushort* __restrict__ Qh, ushort* __restrict__ Kh, ushort* __restrict__ Vt){
  __shared__ __align__(16) ushort shm[5632];
  __shared__ float cs_s[40], sn_s[40];
  int b = blockIdx.x, tid = threadIdx.x;
  if (b < 2048){
    ushort* row = shm;           // 2560 (Q+K only; V handled by transpose blocks)
    int t = b;
    for (int i = tid; i < 320; i += 256)
      *reinterpret_cast<uint4*>(&row[i * 8]) = *reinterpret_cast<const uint4*>(qkv + (size_t)t * 3840 + i * 8);
    if (tid < 40){
      float th = ldin(rope, t * 40 + tid, *flag != 0);
      float c_, s_;
      __sincosf(th, &s_, &c_);   // 40 unique angles per t — compute once, share via LDS
      cs_s[tid] = c_; sn_s[tid] = s_;
    }
    __syncthreads();
    int w = tid;
    if (w < 160){
      int part = w / 80;                 // 0=Q, 1=K
      int hw = w - part * 80;
      int h = hw / 5, dr0 = (hw % 5) * 8;
      const ushort* src = &row[part * HIDDEN + h * HD];
      ushort* dst = (part ? Kh : Qh) + ((size_t)h * TSEQ + t) * HDP;
      ushort o0[8], o1[8];
      for (int d = 0; d < 8; d++){
        float cs = cs_s[dr0 + d], sn = sn_s[dr0 + d];
        float xr = bf2f(src[dr0 + d]);
        float xi = bf2f(src[dr0 + d + 40]);
        o0[d] = f2bf(xr * cs - xi * sn);
        o1[d] = f2bf(xr * sn + xi * cs);
      }
      *reinterpret_cast<uint4*>(dst + dr0)      = *reinterpret_cast<uint4*>(o0);
      *reinterpret_cast<uint4*>(dst + dr0 + 40) = *reinterpret_cast<uint4*>(o1);
    } else if (w < 224){
      int idx = w - 160;                 // 64 items: {Q,K} x 16h x 2seg
      int part = idx >> 5;
      int h = (idx & 31) >> 1, sg = idx & 1;
      ushort* dst = (part ? Kh : Qh) + ((size_t)h * TSEQ + t) * HDP + 80 + sg * 8;
      uint4 z = {0, 0, 0, 0};
      *reinterpret_cast<uint4*>(dst) = z;
    }
  } else {
    int vb = b - 2048;
    int h = vb & 15, t0 = (vb >> 4) * 64;
    const ushort* src = qkv + 2 * HIDDEN + h * HD;
    // tile[64][88]
    for (int w = tid; w < 640; w += 256){
      int r = w / 10, cc = (w % 10) * 8;
      *reinterpret_cast<uint4*>(&shm[r * 88 + cc]) = *reinterpret_cast<const uint4*>(src + (size_t)(t0 + r) * 3840 + cc);
    }
    __syncthreads();
    for (int w = tid; w < 320; w += 256){
      int d = w >> 2, sg = (w & 3) * 16;
      ushort tmp[16];
      for (int i = 0; i < 16; i++) tmp[i] = shm[(sg + i) * 88 + d];
      ushort* dst = Vt + ((size_t)h * HD + d) * TSEQ + t0 + sg;
      *reinterpret_cast<uint4*>(dst)     = *reinterpret_cast<uint4*>(tmp);
      *reinterpret_cast<uint4*>(dst + 8) = *reinterpret_cast<uint4*>(tmp + 8);
    }
  }
}

// ---------------- attention: 16 q/tile, 2 waves split the k-range (additive partials) ------
__launch_bounds__(128, 4)
__global__ void attn_k(const ushort* __restrict__ Qh, const ushort* __restrict__ Kh,
                       const ushort* __restrict__ Vt, const int* __restrict__ seg,
                       const int* __restrict__ segS, const int* __restrict__ segE,
                       ushort* __restrict__ Oh)
{
  __shared__ __align__(16) ushort Pm[2][2][512];   // [wave][dbuf][16*32]
  __shared__ float accS[5][64][4];                 // wave1 partial O
  __shared__ float lsumS[64][4];                   // wave1 partial l
  int tid = threadIdx.x;
  int wave = tid >> 6, lane = tid & 63;
  int quad = lane >> 4, c = lane & 15;
  int b = blockIdx.x;
  int xcd = b & 7, slot = b >> 3;
  int h = slot & 15;
  int t0 = (xcd * 16 + (slot >> 4)) * 16;

  const ushort* Qb = Qh + (size_t)h * TSEQ * HDP;
  const ushort* Kb = Kh + (size_t)h * TSEQ * HDP;
  const ushort* Vb = Vt + (size_t)h * HD * TSEQ;

  bf16x8 aq[3];
  for (int i = 0; i < 3; i++)
    aq[i] = *reinterpret_cast<const bf16x8*>(Qb + (size_t)(t0 + c) * HDP + i * 32 + quad * 8);

  int segq[4];
  for (int rr = 0; rr < 4; rr++) segq[rr] = seg[t0 + quad * 4 + rr];

  int kstart = segS[t0] & ~31;
  int kend   = segE[t0 + 15];

  float lsum[4] = {0.f, 0.f, 0.f, 0.f};
  f32x4 accd[5];
  for (int dt = 0; dt < 5; dt++) accd[dt] = (f32x4){0.f,0.f,0.f,0.f};

  for (int kt = kstart + wave * 32; kt < kend; kt += 64){
    ushort* pm = &Pm[wave][(kt >> 6) & 1][0];
    const ushort* Kp = Kb + (size_t)(kt + c) * HDP + quad * 8;
    const ushort* Vp = Vb + (size_t)c * TSEQ + kt + quad * 8;

    // early-issue V fragment loads (independent of everything until PV)
    bf16x8 bv0 = *reinterpret_cast<const bf16x8*>(Vp);
    bf16x8 bv1 = *reinterpret_cast<const bf16x8*>(Vp + 16 * TSEQ);
    bf16x8 bv2 = *reinterpret_cast<const bf16x8*>(Vp + 32 * TSEQ);
    bf16x8 bv3 = *reinterpret_cast<const bf16x8*>(Vp + 48 * TSEQ);
    bf16x8 bv4 = *reinterpret_cast<const bf16x8*>(Vp + 64 * TSEQ);

    f32x4 s0 = (f32x4){0.f,0.f,0.f,0.f}, s1 = (f32x4){0.f,0.f,0.f,0.f};
    for (int i = 0; i < 3; i++){
      bf16x8 bk0 = *reinterpret_cast<const bf16x8*>(Kp + i * 32);
      bf16x8 bk1 = *reinterpret_cast<const bf16x8*>(Kp + 16 * HDP + i * 32);
      __builtin_amdgcn_s_setprio(1);
      s0 = __builtin_amdgcn_mfma_f32_16x16x32_bf16(aq[i], bk0, s0, 0, 0, 0);
      s1 = __builtin_amdgcn_mfma_f32_16x16x32_bf16(aq[i], bk1, s1, 0, 0, 0);
      __builtin_amdgcn_s_setprio(0);
    }

    int segk0 = seg[kt + c];
    int segk1 = seg[kt + 16 + c];
    for (int rr = 0; rr < 4; rr++){
      bool ok0 = (segq[rr] == segk0);
      bool ok1 = (segq[rr] == segk1);
      float e0 = ok0 ? __expf(fminf(s0[rr] * ATTN_SCALE, 30.f)) : 0.f;
      float e1 = ok1 ? __expf(fminf(s1[rr] * ATTN_SCALE, 30.f)) : 0.f;
      ushort u0 = f2bf(e0), u1 = f2bf(e1);
      lsum[rr] += bf2f(u0) + bf2f(u1);
      pm[(quad * 4 + rr) * 32 + c]      = u0;
      pm[(quad * 4 + rr) * 32 + 16 + c] = u1;
    }
    __builtin_amdgcn_s_waitcnt(0xc07f);   // lgkmcnt(0)
    __builtin_amdgcn_wave_barrier();
    bf16x8 pa = *reinterpret_cast<const bf16x8*>(pm + c * 32 + quad * 8);
    __builtin_amdgcn_s_setprio(1);
    accd[0] = __builtin_amdgcn_mfma_f32_16x16x32_bf16(pa, bv0, accd[0], 0, 0, 0);
    accd[1] = __builtin_amdgcn_mfma_f32_16x16x32_bf16(pa, bv1, accd[1], 0, 0, 0);
    accd[2] = __builtin_amdgcn_mfma_f32_16x16x32_bf16(pa, bv2, accd[2], 0, 0, 0);
    accd[3] = __builtin_amdgcn_mfma_f32_16x16x32_bf16(pa, bv3, accd[3], 0, 0, 0);
    accd[4] = __builtin_amdgcn_mfma_f32_16x16x32_bf16(pa, bv4, accd[4], 0, 0, 0);
    __builtin_amdgcn_s_setprio(0);
  }

  if (wave == 1){
    for (int dt = 0; dt < 5; dt++)
      for (int rr = 0; rr < 4; rr++) accS[dt][lane][rr] = accd[dt][rr];
    for (int rr = 0; rr < 4; rr++) lsumS[lane][rr] = lsum[rr];
  }
  __syncthreads();
  if (wave == 0){
    for (int dt = 0; dt < 5; dt++)
      for (int rr = 0; rr < 4; rr++) accd[dt][rr] += accS[dt][lane][rr];
    for (int rr = 0; rr < 4; rr++) lsum[rr] += lsumS[lane][rr];

    float inv[4];
    for (int rr = 0; rr < 4; rr++){
      float rs = lsum[rr];
      rs += __shfl_xor(rs, 1);
      rs += __shfl_xor(rs, 2);
      rs += __shfl_xor(rs, 4);
      rs += __shfl_xor(rs, 8);
      inv[rr] = (rs > 0.f) ? 1.0f / rs : 0.f;
    }
    for (int dt = 0; dt < 5; dt++)
      for (int rr = 0; rr < 4; rr++){
        int t = t0 + quad * 4 + rr;
        Oh[(size_t)t * HIDDEN + h * HD + dt * 16 + c] = f2bf(accd[dt][rr] * inv[rr]);
      }
  }
}

extern "C" void kernel_launch(void* const* d_in, const int* in_sizes, int n_in,
                              void* d_out, int out_size, void* d_ws, size_t ws_size,
                              hipStream_t stream)
{
  const void* X    = d_in[0];
  const void* rope = d_in[1];
  const int*  seg  = (const int*)d_in[2];
  const void* Wq   = d_in[3];
  const void* bq   = d_in[4];
  const void* Wp   = d_in[5];
  const void* bp   = d_in[6];

  char* ws = (char*)d_ws;
  size_t off = 0;
  auto alloc = [&](size_t bytes){ void* p = ws + off; off += (bytes + 255) & ~(size_t)255; return p; };
  int*    flag = (int*)alloc(4);
  int*    segS = (int*)alloc(TSEQ * 4);
  int*    segE = (int*)alloc(TSEQ * 4);
  ushort* Xb   = (ushort*)alloc((size_t)TSEQ * HIDDEN * 2);          // 5.24 MB (aliased by Oh later)
  ushort* Qh   = (ushort*)alloc((size_t)NH * TSEQ * HDP * 2);        // 6.29 MB
  ushort* Kh   = (ushort*)alloc((size_t)NH * TSEQ * HDP * 2);        // 6.29 MB
  ushort* Vt   = (ushort*)alloc((size_t)NH * HD * TSEQ * 2);         // 5.24 MB
  ushort* WT1  = (ushort*)alloc((size_t)3 * HIDDEN * HIDDEN * 2);    // 9.83 MB
  ushort* WT2  = (ushort*)alloc((size_t)HIDDEN * HIDDEN * 2);        // 3.28 MB
  ushort* qkv  = (ushort*)alloc((size_t)TSEQ * 3 * HIDDEN * 2);      // 15.73 MB
  ushort* Oh   = Xb;   // Xb dead after gemm<0>; attn writes Oh afterwards

  misc_k<<<9, 256, 0, stream>>>((const ushort*)X, seg, flag, segS, segE);
  prep_k<<<2880, 256, 0, stream>>>(flag, X, Wq, Wp, Xb, WT1, WT2);
  gemm_k<0,128><<<dim3(30, 16), 256, 0, stream>>>(Xb, WT1, bq, HIDDEN, 3 * HIDDEN, flag, qkv);
  reshape_k<<<2560, 256, 0, stream>>>(flag, qkv, rope, Qh, Kh, Vt);
  attn_k<<<2048, 128, 0, stream>>>(Qh, Kh, Vt, seg, segS, segE, Oh);
  gemm_k<1,64><<<dim3(20, 16), 256, 0, stream>>>(Oh, WT2, bp, HIDDEN, HIDDEN, flag, d_out);
}